// Round 2
// baseline (91.941 us; speedup 1.0000x reference)
//
#include <hip/hip_runtime.h>

// FCOS GenTargets fused across 5 FPN levels, single dispatch.
// B=8, M=50 boxes, C=80 classes.
// Level grids: (100,128),(50,64),(25,32),(13,16),(7,8) -> HW_TOTAL=17064
// Strides 8,16,32,64,128 ; limits (-1,64],(64,128],(128,256],(256,512],(512,inf]
//
// Output layout (flat float, concatenated in reference return order):
//   [0          , B*HW)          cls_t  (int value stored as float, exact for 0..79)
//   [B*HW       , 2*B*HW)        cnt_t
//   [2*B*HW     , 6*B*HW)        reg_t  (B,HW,4)
//   [6*B*HW     , 6*B*HW+2*HW)   coords (HW,2)
//
// Inputs cls0..cls4 are shape-only in the reference (never read) -> skipped.

#define NB 8
#define NM 50
#define HW_TOTAL 17064
#define BIG_AREA 99999999.0f

__global__ __launch_bounds__(256) void gen_targets_kernel(
    const float* __restrict__ gt,    // [B, M, 4] (x1,y1,x2,y2)
    const int*   __restrict__ cls,   // [B, M]
    float*       __restrict__ out)
{
    __shared__ float4 sbox[NM];
    __shared__ float  scx[NM], scy[NM];
    __shared__ int    scls[NM];

    const int BPB = (HW_TOTAL + 255) / 256;  // 67 blocks per batch
    const int b   = blockIdx.x / BPB;
    const int loc = (blockIdx.x % BPB) * 256 + threadIdx.x;

    // Stage this batch's 50 boxes into LDS once; M-loop reads are
    // wave-uniform -> LDS broadcast, conflict-free.
    if (threadIdx.x < NM) {
        float4 bx = ((const float4*)gt)[b * NM + threadIdx.x];
        sbox[threadIdx.x] = bx;
        scx[threadIdx.x]  = 0.5f * (bx.x + bx.z);   // == (x1+x2)/2 exactly
        scy[threadIdx.x]  = 0.5f * (bx.y + bx.w);
        scls[threadIdx.x] = cls[b * NM + threadIdx.x];
    }
    __syncthreads();

    if (loc >= HW_TOTAL) return;

    // ---- level lookup (wave-uniform except at 4 boundary waves) ----
    int start, wsh; float s, l0, l1;
    if      (loc < 12800) { start = 0;     wsh = 7; s = 8.0f;   l0 = -1.0f;  l1 = 64.0f;     }
    else if (loc < 16000) { start = 12800; wsh = 6; s = 16.0f;  l0 = 64.0f;  l1 = 128.0f;    }
    else if (loc < 16800) { start = 16000; wsh = 5; s = 32.0f;  l0 = 128.0f; l1 = 256.0f;    }
    else if (loc < 17008) { start = 16800; wsh = 4; s = 64.0f;  l0 = 256.0f; l1 = 512.0f;    }
    else                  { start = 17008; wsh = 3; s = 128.0f; l0 = 512.0f; l1 = 999999.0f; }

    const int ll = loc - start;
    const int iy = ll >> wsh;                 // w is a power of 2 at every level
    const int ix = ll & ((1 << wsh) - 1);
    const float xc = (float)ix * s + 0.5f * s;  // exact: int*pow2 + pow2
    const float yc = (float)iy * s + 0.5f * s;
    const float radiu = 1.5f * s;

    // ---- scan 50 boxes: first-occurrence argmin over masked areas ----
    // Strict '<' from +inf == jnp.argmin tie-break (first index wins).
    float best_area = __builtin_inff();
    float bl = 0.f, bt = 0.f, br = 0.f, bb = 0.f;
    int   bcls = 0;

    #pragma unroll 5
    for (int m = 0; m < NM; ++m) {
        const float4 bx = sbox[m];
        const float l = xc - bx.x;
        const float t = yc - bx.y;
        const float r = bx.z - xc;
        const float d = bx.w - yc;

        const float omin = fminf(fminf(l, t), fminf(r, d));
        const float omax = fmaxf(fmaxf(l, t), fmaxf(r, d));
        const float area = (l + r) * (t + d);   // no FMA pattern -> bit-stable masks

        const float coff = fmaxf(fabsf(xc - scx[m]), fabsf(yc - scy[m]));

        const bool mpos = (omin > 0.0f) & (omax > l0) & (omax <= l1) & (coff < radiu);
        const float am  = mpos ? area : BIG_AREA;

        if (am < best_area) {
            best_area = am;
            bl = l; bt = t; br = r; bb = d;
            bcls = scls[m];
        }
    }

    const bool pos = best_area < BIG_AREA;

    // centerness from the argmin box's ltrb (clamps no-op when pos, matching ref)
    const float l_ = fmaxf(bl, 0.0f), t_ = fmaxf(bt, 0.0f);
    const float r_ = fmaxf(br, 0.0f), b_ = fmaxf(bb, 0.0f);
    const float lrmin = fminf(l_, r_), lrmax = fmaxf(l_, r_);
    const float tbmin = fminf(t_, b_), tbmax = fmaxf(t_, b_);
    const float cnt = sqrtf(lrmin * tbmin / (lrmax * tbmax + 1e-10f));

    const int o   = b * HW_TOTAL + loc;
    const int BHW = NB * HW_TOTAL;

    out[o]       = pos ? (float)bcls : 0.0f;   // cls_t (0..79 exact in f32)
    out[BHW + o] = pos ? cnt : -1.0f;          // cnt_t

    const float4 reg = pos ? make_float4(bl, bt, br, bb)
                           : make_float4(-1.f, -1.f, -1.f, -1.f);
    ((float4*)(out + 2 * BHW))[o] = reg;       // reg_t, 16B-aligned store

    if (b == 0) {                               // coords (HW,2), written once
        ((float2*)(out + 6 * BHW))[loc] = make_float2(xc, yc);
    }
}

extern "C" void kernel_launch(void* const* d_in, const int* in_sizes, int n_in,
                              void* d_out, int out_size, void* d_ws, size_t ws_size,
                              hipStream_t stream) {
    // inputs (setup_inputs dict order): cls0..cls4 (shape-only), gt_boxes, classes
    const float* gt  = (const float*)d_in[5];   // [8,50,4] f32, 1600 elems
    const int*   cls = (const int*)d_in[6];     // [8,50]   i32,  400 elems
    float* out = (float*)d_out;

    const int BPB  = (HW_TOTAL + 255) / 256;    // 67
    const int grid = NB * BPB;                   // 536 blocks, 256 thr
    gen_targets_kernel<<<grid, 256, 0, stream>>>(gt, cls, out);
}